// Round 4
// baseline (307.208 us; speedup 1.0000x reference)
//
#include <hip/hip_runtime.h>
#include <hip/hip_bf16.h>

// Performer feature map: out[row][m] = exp( sum_k x[row][k]/scale * W[m][k] ) / sqrt(M)
// rows = B*H*L = 262144, K = D = 128, N = M = 128. Memory-bound (32 FLOP/byte).
// 32x32x16 bf16 MFMA: C/D layout gives two full 128B store lines per scalar store
// instruction -> no LDS transpose epilogue -> Wb-only LDS (34 KB) -> 4 blocks/CU,
// grid 1024 = exactly resident, zero occupancy tail.

typedef __attribute__((ext_vector_type(8)))  short bf16x8;   // MFMA A/B frag (4 VGPRs)
typedef __attribute__((ext_vector_type(16))) float f32x16;   // 32x32 MFMA C/D frag
typedef __attribute__((ext_vector_type(4)))  float f32x4;
typedef __attribute__((ext_vector_type(4)))  short short4v;

#define WPITCH 136  // shorts; 272B rows: b128 B-frag reads 16B-aligned, 8 words/bank (min)

__device__ __forceinline__ short f2bf(float f) {
    // round-to-nearest-even fp32 -> bf16 (finite gaussian inputs; no NaN path)
    union { float f; unsigned u; } v; v.f = f;
    return (short)((v.u + 0x7fffu + ((v.u >> 16) & 1u)) >> 16);
}

__global__ __launch_bounds__(256, 4)
void performer_kernel(const float* __restrict__ x,
                      const float* __restrict__ Wf,
                      float* __restrict__ out,
                      int n_chunks) {   // chunk = 128 rows (4 waves x 32 rows)
    __shared__ short Wb[128 * WPITCH];   // 34816 B -> 4 blocks/CU

    const int tid = threadIdx.x;

    // ---- Stage W -> LDS as bf16, scale 1/128^0.25 folded in. Coalesced f32x4 reads. ----
    {
        const float inv_scale = 0.29730177875068026f;  // 128^-0.25
        #pragma unroll
        for (int i = 0; i < 16; ++i) {
            int idx = i * 256 + tid;          // f32x4 index, 4096 total (128x128 fp32)
            int row = idx >> 5;
            int col = (idx & 31) << 2;
            f32x4 v = reinterpret_cast<const f32x4*>(Wf)[idx];
            short4v s;
            s.x = f2bf(v.x * inv_scale);
            s.y = f2bf(v.y * inv_scale);
            s.z = f2bf(v.z * inv_scale);
            s.w = f2bf(v.w * inv_scale);
            *reinterpret_cast<short4v*>(&Wb[row * WPITCH + col]) = s;
        }
    }
    __syncthreads();

    const int wave = tid >> 6;
    const int lane = tid & 63;
    const int col  = lane & 31;   // A row-in-tile; B col; C/D col
    const int h    = lane >> 5;   // k-half: k = kb*16 + h*8 + j; C/D row += 4*h
    const float LOG2E = 1.44269504088896f;  // out = exp2(proj*log2e - 3.5), 2^-3.5 = 1/sqrt(128)

    for (int chunk = blockIdx.x; chunk < n_chunks; chunk += gridDim.x) {
        const long row0 = (long)chunk * 128 + wave * 32;
        const float* xr = x + (row0 + col) * 128 + h * 8;

        // ---- A tile: 8 k-blocks x 8 floats/lane (2x dwordx4 each, nontemporal) ----
        bf16x8 af[8];
        #pragma unroll
        for (int kb = 0; kb < 8; ++kb) {
            const f32x4* p = reinterpret_cast<const f32x4*>(xr + kb * 16);
            f32x4 a0 = __builtin_nontemporal_load(p);
            f32x4 a1 = __builtin_nontemporal_load(p + 1);
            bf16x8 a;
            a[0] = f2bf(a0.x); a[1] = f2bf(a0.y); a[2] = f2bf(a0.z); a[3] = f2bf(a0.w);
            a[4] = f2bf(a1.x); a[5] = f2bf(a1.y); a[6] = f2bf(a1.z); a[7] = f2bf(a1.w);
            af[kb] = a;
        }

        float* obase = out + row0 * 128;
        #pragma unroll
        for (int nt = 0; nt < 4; ++nt) {   // 4 col-tiles of 32
            f32x16 acc = {0.f};
            #pragma unroll
            for (int kb = 0; kb < 8; ++kb) {
                // B[k][n]: n = nt*32 + col, k = kb*16 + h*8 + j  (8 consecutive shorts)
                bf16x8 bf = *reinterpret_cast<const bf16x8*>(
                    &Wb[(nt * 32 + col) * WPITCH + kb * 16 + h * 8]);
                acc = __builtin_amdgcn_mfma_f32_32x32x16_bf16(af[kb], bf, acc, 0, 0, 0);
            }
            // C/D: col = lane&31, row = (r&3) + 8*(r>>2) + 4*h
            // per store instr: 2 rows x 128 B contiguous aligned lines
            #pragma unroll
            for (int r = 0; r < 16; ++r) {
                int rl = (r & 3) + 8 * (r >> 2) + 4 * h;
                float v = __builtin_exp2f(__builtin_fmaf(acc[r], LOG2E, -3.5f));
                __builtin_nontemporal_store(v, &obase[(long)rl * 128 + nt * 32 + col]);
            }
        }
    }
}

extern "C" void kernel_launch(void* const* d_in, const int* in_sizes, int n_in,
                              void* d_out, int out_size, void* d_ws, size_t ws_size,
                              hipStream_t stream) {
    const float* x  = (const float*)d_in[0];   // (B,H,L,D) fp32
    const float* Wf = (const float*)d_in[1];   // (M,D) fp32
    float* out = (float*)d_out;                // (B,H,L,M) fp32

    const int rows = out_size / 128;           // 262144
    const int n_chunks = rows / 128;           // 2048

    performer_kernel<<<dim3(1024), dim3(256), 0, stream>>>(x, Wf, out, n_chunks);
}